// Round 1
// baseline (1442.321 us; speedup 1.0000x reference)
//
#include <hip/hip_runtime.h>

typedef __attribute__((ext_vector_type(8))) short short8;
typedef __attribute__((ext_vector_type(4))) float f32x4;

__device__ __forceinline__ unsigned short f2bf(float f) {
    unsigned u = __float_as_uint(f);
    u += 0x7fffu + ((u >> 16) & 1u);
    return (unsigned short)(u >> 16);
}

// c[j] = bo[j] + sum_i Wo[j, 512+i] * v_sum[i]   (heads 8..15 contribution, constant)
__global__ __launch_bounds__(256) void k_compute_c(const float* __restrict__ Wo,
        const float* __restrict__ bo, const float* __restrict__ vsum, float* __restrict__ c) {
    int j = blockIdx.x * 256 + threadIdx.x;
    float acc = bo[j];
    const float* row = Wo + (size_t)j * 1024 + 512;
    #pragma unroll 8
    for (int i = 0; i < 512; ++i) acc = fmaf(row[i], vsum[i], acc);
    c[j] = acc;
}

// queries fp32 [b,n,1024] (first 512 cols) -> Qh bf16 [b,h,n,64], scaled by 1/8 (exact in bf16)
__global__ __launch_bounds__(256) void k_convq(const float* __restrict__ q, unsigned short* __restrict__ Qh) {
    int t = blockIdx.x * 256 + threadIdx.x;   // 524288 threads, 4 elems each
    int e = t * 4;
    int c = e & 511;
    int bn = e >> 9;
    float4 v = *reinterpret_cast<const float4*>(q + (size_t)bn * 1024 + c);
    int h = c >> 6, d = c & 63;
    int b = bn >> 11, n = bn & 2047;
    ushort4 o;
    o.x = f2bf(v.x * 0.125f); o.y = f2bf(v.y * 0.125f);
    o.z = f2bf(v.z * 0.125f); o.w = f2bf(v.w * 0.125f);
    *reinterpret_cast<ushort4*>(Qh + (((size_t)(b*8+h) * 2048 + n) * 64 + d)) = o;
}

// G = sigmoid(X @ W^T + b1 + b2), bf16 out. transposed=0: [b,h,n,64]; =1: [b,h,d,2048]
__global__ __launch_bounds__(256) void k_gate(const float* __restrict__ X, const float* __restrict__ W,
        const float* __restrict__ b1, const float* __restrict__ b2,
        unsigned short* __restrict__ out, int transposed) {
    __shared__ __align__(16) unsigned short Xs[64*88];
    __shared__ __align__(16) unsigned short Wsh[64*88];
    int t = threadIdx.x;
    int mbase = blockIdx.x * 64, nbase = blockIdx.y * 64;
    int w = t >> 6, lane = t & 63, l = lane & 15, quad = lane >> 4;
    int srow = t >> 2, sk = (t & 3) * 16;
    f32x4 acc[4] = {};
    for (int kk = 0; kk < 1024; kk += 64) {
        const float4* xs = reinterpret_cast<const float4*>(X + (size_t)(mbase+srow)*1024 + kk + sk);
        const float4* wsp = reinterpret_cast<const float4*>(W + (size_t)(nbase+srow)*1024 + kk + sk);
        #pragma unroll
        for (int i = 0; i < 4; ++i) {
            float4 xv = xs[i], wv = wsp[i];
            ushort4 xo, wo;
            xo.x=f2bf(xv.x); xo.y=f2bf(xv.y); xo.z=f2bf(xv.z); xo.w=f2bf(xv.w);
            wo.x=f2bf(wv.x); wo.y=f2bf(wv.y); wo.z=f2bf(wv.z); wo.w=f2bf(wv.w);
            *reinterpret_cast<ushort4*>(&Xs[srow*88 + sk + i*4]) = xo;
            *reinterpret_cast<ushort4*>(&Wsh[srow*88 + sk + i*4]) = wo;
        }
        __syncthreads();
        short8 a0 = *reinterpret_cast<const short8*>(&Xs[(w*16+l)*88 + quad*8]);
        short8 a1 = *reinterpret_cast<const short8*>(&Xs[(w*16+l)*88 + 32 + quad*8]);
        #pragma unroll
        for (int nt = 0; nt < 4; ++nt) {
            short8 bq0 = *reinterpret_cast<const short8*>(&Wsh[(l+16*nt)*88 + quad*8]);
            short8 bq1 = *reinterpret_cast<const short8*>(&Wsh[(l+16*nt)*88 + 32 + quad*8]);
            acc[nt] = __builtin_amdgcn_mfma_f32_16x16x32_bf16(a0, bq0, acc[nt], 0, 0, 0);
            acc[nt] = __builtin_amdgcn_mfma_f32_16x16x32_bf16(a1, bq1, acc[nt], 0, 0, 0);
        }
        __syncthreads();
    }
    #pragma unroll
    for (int nt = 0; nt < 4; ++nt) {
        int col = nbase + l + 16*nt;
        float bias = b1[col] + b2[col];
        #pragma unroll
        for (int reg = 0; reg < 4; ++reg) {
            int m = mbase + w*16 + quad*4 + reg;
            float x = acc[nt][reg] + bias;
            float g = 1.0f / (1.0f + __expf(-x));
            int b = m >> 11, n = m & 2047;
            int h = col >> 6, d = col & 63;
            size_t addr = transposed ? (((size_t)(b*8+h)*64 + d)*2048 + n)
                                     : (((size_t)(b*8+h)*2048 + n)*64 + d);
            out[addr] = f2bf(g);
        }
    }
}

// Flash attention, heads 0..7 only. Block = (b,h,qtile of 64). 4 waves, 16 q-rows each.
__global__ __launch_bounds__(256) void k_attn(const unsigned short* __restrict__ Qh,
        const unsigned short* __restrict__ Kh, const unsigned short* __restrict__ Vt,
        const float* __restrict__ attw, const int* __restrict__ mask,
        unsigned short* __restrict__ O) {
    __shared__ __align__(16) unsigned short Ps[4*16*88];
    int bx = blockIdx.x;
    int qt = bx & 31, h = (bx >> 5) & 7, b = bx >> 8;
    int t = threadIdx.x, w = t >> 6, lane = t & 63, l = lane & 15, quad = lane >> 4;
    int qbase = qt * 64;
    int bh = b*8 + h;
    const unsigned short* qp = Qh + ((size_t)bh*2048 + qbase + w*16 + l)*64 + quad*8;
    short8 qf0 = *reinterpret_cast<const short8*>(qp);
    short8 qf1 = *reinterpret_cast<const short8*>(qp + 32);
    float m_r[4], l_r[4];
    f32x4 oacc[4] = {};
    #pragma unroll
    for (int r = 0; r < 4; ++r) { m_r[r] = -1e30f; l_r[r] = 0.0f; }
    unsigned short* Pw = &Ps[w * 16*88];
    int qrc = qbase + w*16 + quad*4;
    for (int kt = 0; kt < 32; ++kt) {
        int kbase = kt * 64;
        f32x4 s[4] = {};
        #pragma unroll
        for (int nt = 0; nt < 4; ++nt) {
            const unsigned short* kp = Kh + ((size_t)bh*2048 + kbase + l + 16*nt)*64 + quad*8;
            short8 k0 = *reinterpret_cast<const short8*>(kp);
            short8 k1 = *reinterpret_cast<const short8*>(kp + 32);
            s[nt] = __builtin_amdgcn_mfma_f32_16x16x32_bf16(qf0, k0, s[nt], 0, 0, 0);
            s[nt] = __builtin_amdgcn_mfma_f32_16x16x32_bf16(qf1, k1, s[nt], 0, 0, 0);
        }
        // scores already carry 1/sqrt(64) via Q prescale; apply weights then mask
        float sv[4][4];
        #pragma unroll
        for (int reg = 0; reg < 4; ++reg) {
            size_t off = ((size_t)((b*16 + h)*2048 + qrc + reg))*2048 + kbase + l;
            const float* wr = attw + off;
            const int* mr = mask + off;
            #pragma unroll
            for (int nt = 0; nt < 4; ++nt) {
                float wg = wr[16*nt];
                int mk = mr[16*nt];
                sv[nt][reg] = mk ? -1e30f : s[nt][reg] * wg;
            }
        }
        float alpha[4];
        #pragma unroll
        for (int reg = 0; reg < 4; ++reg) {
            float rm = fmaxf(fmaxf(sv[0][reg], sv[1][reg]), fmaxf(sv[2][reg], sv[3][reg]));
            rm = fmaxf(rm, __shfl_xor(rm, 1));
            rm = fmaxf(rm, __shfl_xor(rm, 2));
            rm = fmaxf(rm, __shfl_xor(rm, 4));
            rm = fmaxf(rm, __shfl_xor(rm, 8));
            float mnew = fmaxf(m_r[reg], rm);
            alpha[reg] = __expf(m_r[reg] - mnew);
            m_r[reg] = mnew;
            float rs = 0.0f;
            #pragma unroll
            for (int nt = 0; nt < 4; ++nt) {
                float p = __expf(sv[nt][reg] - mnew);
                sv[nt][reg] = p;
                rs += p;
            }
            rs += __shfl_xor(rs, 1);
            rs += __shfl_xor(rs, 2);
            rs += __shfl_xor(rs, 4);
            rs += __shfl_xor(rs, 8);
            l_r[reg] = l_r[reg] * alpha[reg] + rs;
        }
        #pragma unroll
        for (int dt = 0; dt < 4; ++dt)
            #pragma unroll
            for (int reg = 0; reg < 4; ++reg)
                oacc[dt][reg] *= alpha[reg];
        // P: C-layout -> LDS -> A-layout (per-wave region, no block barrier needed)
        #pragma unroll
        for (int reg = 0; reg < 4; ++reg)
            #pragma unroll
            for (int nt = 0; nt < 4; ++nt)
                Pw[(quad*4+reg)*88 + l + 16*nt] = f2bf(sv[nt][reg]);
        __builtin_amdgcn_s_waitcnt(0xC07F);  // lgkmcnt(0): DS writes visible before reads
        short8 pf0 = *reinterpret_cast<const short8*>(&Pw[l*88 + quad*8]);
        short8 pf1 = *reinterpret_cast<const short8*>(&Pw[l*88 + 32 + quad*8]);
        #pragma unroll
        for (int dt = 0; dt < 4; ++dt) {
            const unsigned short* vp = Vt + ((size_t)bh*64 + l + 16*dt)*2048 + kbase + quad*8;
            short8 v0 = *reinterpret_cast<const short8*>(vp);
            short8 v1 = *reinterpret_cast<const short8*>(vp + 32);
            oacc[dt] = __builtin_amdgcn_mfma_f32_16x16x32_bf16(pf0, v0, oacc[dt], 0, 0, 0);
            oacc[dt] = __builtin_amdgcn_mfma_f32_16x16x32_bf16(pf1, v1, oacc[dt], 0, 0, 0);
        }
    }
    #pragma unroll
    for (int reg = 0; reg < 4; ++reg) {
        float inv = 1.0f / l_r[reg];
        int qr = qbase + w*16 + quad*4 + reg;
        #pragma unroll
        for (int dt = 0; dt < 4; ++dt) {
            int col = h*64 + l + 16*dt;
            O[((size_t)b*2048 + qr)*512 + col] = f2bf(oacc[dt][reg] * inv);
        }
    }
}

// out[m,n] = sum_{k<512} O[m,k]*Wo[n,k] + c[n]
__global__ __launch_bounds__(256) void k_proj(const unsigned short* __restrict__ O,
        const float* __restrict__ Wo, const float* __restrict__ c, float* __restrict__ out) {
    __shared__ __align__(16) unsigned short Wsh[64*88];
    int t = threadIdx.x;
    int mb = blockIdx.x * 64, nb = blockIdx.y * 64;
    int w = t >> 6, lane = t & 63, l = lane & 15, quad = lane >> 4;
    int srow = t >> 2, sk = (t & 3) * 16;
    f32x4 acc[4] = {};
    for (int kb = 0; kb < 512; kb += 64) {
        const float4* wp = reinterpret_cast<const float4*>(Wo + (size_t)(nb+srow)*1024 + kb + sk);
        #pragma unroll
        for (int i = 0; i < 4; ++i) {
            float4 wv = wp[i];
            ushort4 wo2;
            wo2.x=f2bf(wv.x); wo2.y=f2bf(wv.y); wo2.z=f2bf(wv.z); wo2.w=f2bf(wv.w);
            *reinterpret_cast<ushort4*>(&Wsh[srow*88 + sk + i*4]) = wo2;
        }
        __syncthreads();
        const unsigned short* op = O + (size_t)(mb + w*16 + l)*512 + kb + quad*8;
        short8 a0 = *reinterpret_cast<const short8*>(op);
        short8 a1 = *reinterpret_cast<const short8*>(op + 32);
        #pragma unroll
        for (int nt = 0; nt < 4; ++nt) {
            short8 b0 = *reinterpret_cast<const short8*>(&Wsh[(l+16*nt)*88 + quad*8]);
            short8 b1 = *reinterpret_cast<const short8*>(&Wsh[(l+16*nt)*88 + 32 + quad*8]);
            acc[nt] = __builtin_amdgcn_mfma_f32_16x16x32_bf16(a0, b0, acc[nt], 0, 0, 0);
            acc[nt] = __builtin_amdgcn_mfma_f32_16x16x32_bf16(a1, b1, acc[nt], 0, 0, 0);
        }
        __syncthreads();
    }
    #pragma unroll
    for (int nt = 0; nt < 4; ++nt) {
        int coln = nb + l + 16*nt;
        float cv = c[coln];
        #pragma unroll
        for (int reg = 0; reg < 4; ++reg) {
            int row = mb + w*16 + quad*4 + reg;
            out[(size_t)row*1024 + coln] = acc[nt][reg] + cv;
        }
    }
}

extern "C" void kernel_launch(void* const* d_in, const int* in_sizes, int n_in,
                              void* d_out, int out_size, void* d_ws, size_t ws_size,
                              hipStream_t stream) {
    const float* queries = (const float*)d_in[0];
    const float* keys    = (const float*)d_in[1];
    const float* values  = (const float*)d_in[2];
    const int*   mask    = (const int*)d_in[3];
    const float* attw    = (const float*)d_in[4];
    const float* Wk_f    = (const float*)d_in[5];
    const float* bk_f    = (const float*)d_in[6];
    const float* kf_bias = (const float*)d_in[7];
    const float* Wv_f    = (const float*)d_in[8];
    const float* bv_f    = (const float*)d_in[9];
    const float* vf_bias = (const float*)d_in[10];
    // d_in[11] = k_sum: unused (heads>=8 output is exactly v_sum, independent of scores)
    const float* v_sum   = (const float*)d_in[12];
    const float* Wo      = (const float*)d_in[13];
    const float* bo      = (const float*)d_in[14];
    float* out = (float*)d_out;

    char* ws = (char*)d_ws;
    float* cvec = (float*)ws;                                   // 1024 f32
    unsigned short* Qh = (unsigned short*)(ws + 4096);          // 4 MB
    unsigned short* Kh = Qh + (size_t)2*8*2048*64;              // 4 MB
    unsigned short* Vt = Kh + (size_t)2*8*2048*64;              // 4 MB
    unsigned short* Ob = Vt + (size_t)2*8*2048*64;              // 4 MB

    hipLaunchKernelGGL(k_compute_c, dim3(4), dim3(256), 0, stream, Wo, bo, v_sum, cvec);
    hipLaunchKernelGGL(k_convq, dim3(2048), dim3(256), 0, stream, queries, Qh);
    hipLaunchKernelGGL(k_gate, dim3(64, 8), dim3(256), 0, stream, keys, Wk_f, bk_f, kf_bias, Kh, 0);
    hipLaunchKernelGGL(k_gate, dim3(64, 8), dim3(256), 0, stream, values, Wv_f, bv_f, vf_bias, Vt, 1);
    hipLaunchKernelGGL(k_attn, dim3(512), dim3(256), 0, stream, Qh, Kh, Vt, attw, mask, Ob);
    hipLaunchKernelGGL(k_proj, dim3(64, 16), dim3(256), 0, stream, Ob, Wo, cvec, out);
}

// Round 2
// 1108.052 us; speedup vs baseline: 1.3017x; 1.3017x over previous
//
#include <hip/hip_runtime.h>

typedef __attribute__((ext_vector_type(8))) short short8;
typedef __attribute__((ext_vector_type(4))) float f32x4;

__device__ __forceinline__ unsigned short f2bf(float f) {
    unsigned u = __float_as_uint(f);
    u += 0x7fffu + ((u >> 16) & 1u);
    return (unsigned short)(u >> 16);
}

// c[j] = bo[j] + sum_i Wo[j, 512+i] * v_sum[i]  (heads 8..15 contribution, constant)
// one wave per j, coalesced reads, shuffle reduce
__global__ __launch_bounds__(256) void k_compute_c(const float* __restrict__ Wo,
        const float* __restrict__ bo, const float* __restrict__ vsum, float* __restrict__ c) {
    int w = threadIdx.x >> 6, lane = threadIdx.x & 63;
    int j = blockIdx.x * 4 + w;
    const float* row = Wo + (size_t)j * 1024 + 512;
    float acc = 0.0f;
    #pragma unroll
    for (int i = 0; i < 8; ++i) acc = fmaf(row[lane + 64*i], vsum[lane + 64*i], acc);
    #pragma unroll
    for (int off = 32; off; off >>= 1) acc += __shfl_xor(acc, off);
    if (lane == 0) c[j] = acc + bo[j];
}

// queries fp32 [b,n,1024] (first 512 cols) -> Qh bf16 [b,h,n,64], scaled by 1/8 (exact in bf16)
__global__ __launch_bounds__(256) void k_convq(const float* __restrict__ q, unsigned short* __restrict__ Qh) {
    int t = blockIdx.x * 256 + threadIdx.x;
    int e = t * 4;
    int c = e & 511;
    int bn = e >> 9;
    float4 v = *reinterpret_cast<const float4*>(q + (size_t)bn * 1024 + c);
    int h = c >> 6, d = c & 63;
    int b = bn >> 11, n = bn & 2047;
    ushort4 o;
    o.x = f2bf(v.x * 0.125f); o.y = f2bf(v.y * 0.125f);
    o.z = f2bf(v.z * 0.125f); o.w = f2bf(v.w * 0.125f);
    *reinterpret_cast<ushort4*>(Qh + (((size_t)(b*8+h) * 2048 + n) * 64 + d)) = o;
}

// G = sigmoid(X @ W^T + b1 + b2), bf16 out, layout [b,h,n,64] (coalesced)
__global__ __launch_bounds__(256) void k_gate(const float* __restrict__ X, const float* __restrict__ W,
        const float* __restrict__ b1, const float* __restrict__ b2,
        unsigned short* __restrict__ out) {
    __shared__ __align__(16) unsigned short Xs[64*88];
    __shared__ __align__(16) unsigned short Wsh[64*88];
    int t = threadIdx.x;
    int mbase = blockIdx.x * 64, nbase = blockIdx.y * 64;
    int w = t >> 6, lane = t & 63, l = lane & 15, quad = lane >> 4;
    int srow = t >> 2, sk = (t & 3) * 16;
    f32x4 acc[4] = {};
    for (int kk = 0; kk < 1024; kk += 64) {
        const float4* xs = reinterpret_cast<const float4*>(X + (size_t)(mbase+srow)*1024 + kk + sk);
        const float4* wsp = reinterpret_cast<const float4*>(W + (size_t)(nbase+srow)*1024 + kk + sk);
        #pragma unroll
        for (int i = 0; i < 4; ++i) {
            float4 xv = xs[i], wv = wsp[i];
            ushort4 xo, wo;
            xo.x=f2bf(xv.x); xo.y=f2bf(xv.y); xo.z=f2bf(xv.z); xo.w=f2bf(xv.w);
            wo.x=f2bf(wv.x); wo.y=f2bf(wv.y); wo.z=f2bf(wv.z); wo.w=f2bf(wv.w);
            *reinterpret_cast<ushort4*>(&Xs[srow*88 + sk + i*4]) = xo;
            *reinterpret_cast<ushort4*>(&Wsh[srow*88 + sk + i*4]) = wo;
        }
        __syncthreads();
        short8 a0 = *reinterpret_cast<const short8*>(&Xs[(w*16+l)*88 + quad*8]);
        short8 a1 = *reinterpret_cast<const short8*>(&Xs[(w*16+l)*88 + 32 + quad*8]);
        #pragma unroll
        for (int nt = 0; nt < 4; ++nt) {
            short8 bq0 = *reinterpret_cast<const short8*>(&Wsh[(l+16*nt)*88 + quad*8]);
            short8 bq1 = *reinterpret_cast<const short8*>(&Wsh[(l+16*nt)*88 + 32 + quad*8]);
            acc[nt] = __builtin_amdgcn_mfma_f32_16x16x32_bf16(a0, bq0, acc[nt], 0, 0, 0);
            acc[nt] = __builtin_amdgcn_mfma_f32_16x16x32_bf16(a1, bq1, acc[nt], 0, 0, 0);
        }
        __syncthreads();
    }
    #pragma unroll
    for (int nt = 0; nt < 4; ++nt) {
        int col = nbase + l + 16*nt;
        float bias = b1[col] + b2[col];
        #pragma unroll
        for (int reg = 0; reg < 4; ++reg) {
            int m = mbase + w*16 + quad*4 + reg;
            float x = acc[nt][reg] + bias;
            float g = 1.0f / (1.0f + __expf(-x));
            int b = m >> 11, n = m & 2047;
            int h = col >> 6, d = col & 63;
            out[(((size_t)(b*8+h)*2048 + n)*64 + d)] = f2bf(g);
        }
    }
}

// Vt[b,h,d,2048] = transpose of Vn[b,h,n,64], LDS-tiled, coalesced both sides
__global__ __launch_bounds__(256) void k_vtrans(const unsigned short* __restrict__ Vn,
        unsigned short* __restrict__ Vt) {
    __shared__ __align__(16) unsigned short T[64*72];
    int bh = blockIdx.y;
    int n0 = blockIdx.x * 64;
    int t = threadIdx.x;
    int r = t >> 2, c = (t & 3) * 16;
    const unsigned short* src = Vn + ((size_t)bh*2048 + n0 + r)*64 + c;
    short8 v0 = *reinterpret_cast<const short8*>(src);
    short8 v1 = *reinterpret_cast<const short8*>(src + 8);
    *reinterpret_cast<short8*>(&T[r*72 + c]) = v0;
    *reinterpret_cast<short8*>(&T[r*72 + c + 8]) = v1;
    __syncthreads();
    int d = t >> 2, oc = (t & 3) * 16;
    unsigned short tmp[16];
    #pragma unroll
    for (int j = 0; j < 16; ++j) tmp[j] = T[(oc + j)*72 + d];
    unsigned short* dst = Vt + ((size_t)bh*64 + d)*2048 + n0 + oc;
    *reinterpret_cast<short8*>(dst) = *reinterpret_cast<short8*>(&tmp[0]);
    *reinterpret_cast<short8*>(dst + 8) = *reinterpret_cast<short8*>(&tmp[8]);
}

// Flash attention, heads 0..7. Block = (b,h,qtile of 64). attw+mask fused & LDS-staged,
// double-buffered: global dwordx4 loads for kt+1 issued before compute(kt).
#define NEGBIG -1e30f
__global__ __launch_bounds__(256) void k_attn(const unsigned short* __restrict__ Qh,
        const unsigned short* __restrict__ Kh, const unsigned short* __restrict__ Vt,
        const float* __restrict__ attw, const int* __restrict__ mask,
        unsigned short* __restrict__ O) {
    __shared__ __align__(16) float Fs[2][64*68];        // fused (mask? -1e30 : attw) tiles
    __shared__ __align__(16) unsigned short Ps[4*16*88];
    int bx = blockIdx.x;
    int qt = bx & 31, h = (bx >> 5) & 7, b = bx >> 8;
    int t = threadIdx.x, w = t >> 6, lane = t & 63, l = lane & 15, quad = lane >> 4;
    int qbase = qt * 64;
    int bh = b*8 + h;
    const unsigned short* qp = Qh + ((size_t)bh*2048 + qbase + w*16 + l)*64 + quad*8;
    short8 qf0 = *reinterpret_cast<const short8*>(qp);
    short8 qf1 = *reinterpret_cast<const short8*>(qp + 32);
    float m_r[4], l_r[4];
    f32x4 oacc[4] = {};
    #pragma unroll
    for (int r = 0; r < 4; ++r) { m_r[r] = NEGBIG; l_r[r] = 0.0f; }
    unsigned short* Pw = &Ps[w * 16*88];

    // staging map: thread -> (row srow of 64 q-rows, 16 consecutive k-cols)
    int srow = t >> 2, scol = (t & 3) * 16;
    const float* awp = attw + ((size_t)((b*16 + h)*2048 + qbase + srow))*2048 + scol;
    const int*   mkp = mask + ((size_t)((b*16 + h)*2048 + qbase + srow))*2048 + scol;
    float4 aw[4];
    int4   mkv[4];

    // prologue: tile 0
    #pragma unroll
    for (int i = 0; i < 4; ++i) {
        aw[i]  = *reinterpret_cast<const float4*>(awp + i*4);
        mkv[i] = *reinterpret_cast<const int4*>(mkp + i*4);
    }
    {
        float* dst = &Fs[0][srow*68 + scol];
        #pragma unroll
        for (int i = 0; i < 4; ++i) {
            float4 fv;
            fv.x = mkv[i].x ? NEGBIG : aw[i].x;
            fv.y = mkv[i].y ? NEGBIG : aw[i].y;
            fv.z = mkv[i].z ? NEGBIG : aw[i].z;
            fv.w = mkv[i].w ? NEGBIG : aw[i].w;
            *reinterpret_cast<float4*>(dst + i*4) = fv;
        }
    }
    __syncthreads();

    for (int kt = 0; kt < 32; ++kt) {
        int kbase = kt * 64;
        // issue global loads for kt+1 (latency hidden behind compute below)
        if (kt < 31) {
            const float* a2 = awp + (kt+1)*64;
            const int*   m2 = mkp + (kt+1)*64;
            #pragma unroll
            for (int i = 0; i < 4; ++i) {
                aw[i]  = *reinterpret_cast<const float4*>(a2 + i*4);
                mkv[i] = *reinterpret_cast<const int4*>(m2 + i*4);
            }
        }
        // QK^T
        f32x4 s[4] = {};
        #pragma unroll
        for (int nt = 0; nt < 4; ++nt) {
            const unsigned short* kp = Kh + ((size_t)bh*2048 + kbase + l + 16*nt)*64 + quad*8;
            short8 k0 = *reinterpret_cast<const short8*>(kp);
            short8 k1 = *reinterpret_cast<const short8*>(kp + 32);
            s[nt] = __builtin_amdgcn_mfma_f32_16x16x32_bf16(qf0, k0, s[nt], 0, 0, 0);
            s[nt] = __builtin_amdgcn_mfma_f32_16x16x32_bf16(qf1, k1, s[nt], 0, 0, 0);
        }
        // fused weight/mask from LDS (C-layout reads, stride 68 -> at most free 2-way)
        const float* fbuf = &Fs[kt & 1][0];
        float sv[4][4];
        #pragma unroll
        for (int reg = 0; reg < 4; ++reg) {
            int rowoff = (w*16 + quad*4 + reg) * 68 + l;
            #pragma unroll
            for (int nt = 0; nt < 4; ++nt) {
                float f = fbuf[rowoff + 16*nt];
                sv[nt][reg] = (f < -5e29f) ? NEGBIG : s[nt][reg] * f;
            }
        }
        float alpha[4];
        #pragma unroll
        for (int reg = 0; reg < 4; ++reg) {
            float rm = fmaxf(fmaxf(sv[0][reg], sv[1][reg]), fmaxf(sv[2][reg], sv[3][reg]));
            rm = fmaxf(rm, __shfl_xor(rm, 1));
            rm = fmaxf(rm, __shfl_xor(rm, 2));
            rm = fmaxf(rm, __shfl_xor(rm, 4));
            rm = fmaxf(rm, __shfl_xor(rm, 8));
            float mnew = fmaxf(m_r[reg], rm);
            alpha[reg] = __expf(m_r[reg] - mnew);
            m_r[reg] = mnew;
            float rs = 0.0f;
            #pragma unroll
            for (int nt = 0; nt < 4; ++nt) {
                float p = __expf(sv[nt][reg] - mnew);
                sv[nt][reg] = p;
                rs += p;
            }
            rs += __shfl_xor(rs, 1);
            rs += __shfl_xor(rs, 2);
            rs += __shfl_xor(rs, 4);
            rs += __shfl_xor(rs, 8);
            l_r[reg] = l_r[reg] * alpha[reg] + rs;
        }
        #pragma unroll
        for (int dt = 0; dt < 4; ++dt)
            #pragma unroll
            for (int reg = 0; reg < 4; ++reg)
                oacc[dt][reg] *= alpha[reg];
        // P: C-layout -> LDS -> A-layout (per-wave region)
        #pragma unroll
        for (int reg = 0; reg < 4; ++reg)
            #pragma unroll
            for (int nt = 0; nt < 4; ++nt)
                Pw[(quad*4+reg)*88 + l + 16*nt] = f2bf(sv[nt][reg]);
        __builtin_amdgcn_s_waitcnt(0xC07F);  // lgkmcnt(0)
        short8 pf0 = *reinterpret_cast<const short8*>(&Pw[l*88 + quad*8]);
        short8 pf1 = *reinterpret_cast<const short8*>(&Pw[l*88 + 32 + quad*8]);
        #pragma unroll
        for (int dt = 0; dt < 4; ++dt) {
            const unsigned short* vp = Vt + ((size_t)bh*64 + l + 16*dt)*2048 + kbase + quad*8;
            short8 v0 = *reinterpret_cast<const short8*>(vp);
            short8 v1 = *reinterpret_cast<const short8*>(vp + 32);
            oacc[dt] = __builtin_amdgcn_mfma_f32_16x16x32_bf16(pf0, v0, oacc[dt], 0, 0, 0);
            oacc[dt] = __builtin_amdgcn_mfma_f32_16x16x32_bf16(pf1, v1, oacc[dt], 0, 0, 0);
        }
        // commit kt+1 tile into the other buffer (read last at kt-1; safe pre-barrier)
        if (kt < 31) {
            float* dst = &Fs[(kt+1) & 1][srow*68 + scol];
            #pragma unroll
            for (int i = 0; i < 4; ++i) {
                float4 fv;
                fv.x = mkv[i].x ? NEGBIG : aw[i].x;
                fv.y = mkv[i].y ? NEGBIG : aw[i].y;
                fv.z = mkv[i].z ? NEGBIG : aw[i].z;
                fv.w = mkv[i].w ? NEGBIG : aw[i].w;
                *reinterpret_cast<float4*>(dst + i*4) = fv;
            }
        }
        __syncthreads();
    }
    #pragma unroll
    for (int reg = 0; reg < 4; ++reg) {
        float inv = 1.0f / l_r[reg];
        int qr = qbase + w*16 + quad*4 + reg;
        #pragma unroll
        for (int dt = 0; dt < 4; ++dt) {
            int col = h*64 + l + 16*dt;
            O[((size_t)b*2048 + qr)*512 + col] = f2bf(oacc[dt][reg] * inv);
        }
    }
}

// out[m,n] = sum_{k<512} O[m,k]*Wo[n,k] + c[n]
__global__ __launch_bounds__(256) void k_proj(const unsigned short* __restrict__ O,
        const float* __restrict__ Wo, const float* __restrict__ c, float* __restrict__ out) {
    __shared__ __align__(16) unsigned short Wsh[64*88];
    int t = threadIdx.x;
    int mb = blockIdx.x * 64, nb = blockIdx.y * 64;
    int w = t >> 6, lane = t & 63, l = lane & 15, quad = lane >> 4;
    int srow = t >> 2, sk = (t & 3) * 16;
    f32x4 acc[4] = {};
    for (int kb = 0; kb < 512; kb += 64) {
        const float4* wp = reinterpret_cast<const float4*>(Wo + (size_t)(nb+srow)*1024 + kb + sk);
        #pragma unroll
        for (int i = 0; i < 4; ++i) {
            float4 wv = wp[i];
            ushort4 wo2;
            wo2.x=f2bf(wv.x); wo2.y=f2bf(wv.y); wo2.z=f2bf(wv.z); wo2.w=f2bf(wv.w);
            *reinterpret_cast<ushort4*>(&Wsh[srow*88 + sk + i*4]) = wo2;
        }
        __syncthreads();
        const unsigned short* op = O + (size_t)(mb + w*16 + l)*512 + kb + quad*8;
        short8 a0 = *reinterpret_cast<const short8*>(op);
        short8 a1 = *reinterpret_cast<const short8*>(op + 32);
        #pragma unroll
        for (int nt = 0; nt < 4; ++nt) {
            short8 b0 = *reinterpret_cast<const short8*>(&Wsh[(l+16*nt)*88 + quad*8]);
            short8 b1 = *reinterpret_cast<const short8*>(&Wsh[(l+16*nt)*88 + 32 + quad*8]);
            acc[nt] = __builtin_amdgcn_mfma_f32_16x16x32_bf16(a0, b0, acc[nt], 0, 0, 0);
            acc[nt] = __builtin_amdgcn_mfma_f32_16x16x32_bf16(a1, b1, acc[nt], 0, 0, 0);
        }
        __syncthreads();
    }
    #pragma unroll
    for (int nt = 0; nt < 4; ++nt) {
        int coln = nb + l + 16*nt;
        float cv = c[coln];
        #pragma unroll
        for (int reg = 0; reg < 4; ++reg) {
            int row = mb + w*16 + quad*4 + reg;
            out[(size_t)row*1024 + coln] = acc[nt][reg] + cv;
        }
    }
}

extern "C" void kernel_launch(void* const* d_in, const int* in_sizes, int n_in,
                              void* d_out, int out_size, void* d_ws, size_t ws_size,
                              hipStream_t stream) {
    const float* queries = (const float*)d_in[0];
    const float* keys    = (const float*)d_in[1];
    const float* values  = (const float*)d_in[2];
    const int*   mask    = (const int*)d_in[3];
    const float* attw    = (const float*)d_in[4];
    const float* Wk_f    = (const float*)d_in[5];
    const float* bk_f    = (const float*)d_in[6];
    const float* kf_bias = (const float*)d_in[7];
    const float* Wv_f    = (const float*)d_in[8];
    const float* bv_f    = (const float*)d_in[9];
    const float* vf_bias = (const float*)d_in[10];
    // d_in[11] = k_sum: unused (heads>=8 output is exactly v_sum)
    const float* v_sum   = (const float*)d_in[12];
    const float* Wo      = (const float*)d_in[13];
    const float* bo      = (const float*)d_in[14];
    float* out = (float*)d_out;

    char* ws = (char*)d_ws;
    float* cvec = (float*)ws;                                   // 4 KB
    unsigned short* Qh = (unsigned short*)(ws + 4096);          // 4 MB
    unsigned short* Kh = Qh + (size_t)2*8*2048*64;              // 4 MB
    unsigned short* Vt = Kh + (size_t)2*8*2048*64;              // 4 MB
    unsigned short* Vn = Vt + (size_t)2*8*2048*64;              // 4 MB (aliased: Ob reuses Vn)
    unsigned short* Ob = Vn;                                    // attn output overwrites Vn

    hipLaunchKernelGGL(k_compute_c, dim3(256), dim3(256), 0, stream, Wo, bo, v_sum, cvec);
    hipLaunchKernelGGL(k_convq, dim3(2048), dim3(256), 0, stream, queries, Qh);
    hipLaunchKernelGGL(k_gate, dim3(64, 8), dim3(256), 0, stream, keys, Wk_f, bk_f, kf_bias, Kh);
    hipLaunchKernelGGL(k_gate, dim3(64, 8), dim3(256), 0, stream, values, Wv_f, bv_f, vf_bias, Vn);
    hipLaunchKernelGGL(k_vtrans, dim3(32, 16), dim3(256), 0, stream, Vn, Vt);
    hipLaunchKernelGGL(k_attn, dim3(512), dim3(256), 0, stream, Qh, Kh, Vt, attw, mask, Ob);
    hipLaunchKernelGGL(k_proj, dim3(64, 16), dim3(256), 0, stream, Ob, Wo, cvec, out);
}

// Round 3
// 1075.374 us; speedup vs baseline: 1.3412x; 1.0304x over previous
//
#include <hip/hip_runtime.h>

typedef __attribute__((ext_vector_type(8))) short short8;
typedef __attribute__((ext_vector_type(4))) float f32x4;

__device__ __forceinline__ unsigned short f2bf(float f) {
    unsigned u = __float_as_uint(f);
    u += 0x7fffu + ((u >> 16) & 1u);
    return (unsigned short)(u >> 16);
}

// c[j] = bo[j] + sum_i Wo[j, 512+i] * v_sum[i]  (heads 8..15 contribution, constant)
__global__ __launch_bounds__(256) void k_compute_c(const float* __restrict__ Wo,
        const float* __restrict__ bo, const float* __restrict__ vsum, float* __restrict__ c) {
    int w = threadIdx.x >> 6, lane = threadIdx.x & 63;
    int j = blockIdx.x * 4 + w;
    const float* row = Wo + (size_t)j * 1024 + 512;
    float acc = 0.0f;
    #pragma unroll
    for (int i = 0; i < 8; ++i) acc = fmaf(row[lane + 64*i], vsum[lane + 64*i], acc);
    #pragma unroll
    for (int off = 32; off; off >>= 1) acc += __shfl_xor(acc, off);
    if (lane == 0) c[j] = acc + bo[j];
}

// queries fp32 [b,n,1024] (first 512 cols) -> Qh bf16 [b,h,n,64], scaled by 1/8
__global__ __launch_bounds__(256) void k_convq(const float* __restrict__ q, unsigned short* __restrict__ Qh) {
    int t = blockIdx.x * 256 + threadIdx.x;
    int e = t * 4;
    int c = e & 511;
    int bn = e >> 9;
    float4 v = *reinterpret_cast<const float4*>(q + (size_t)bn * 1024 + c);
    int h = c >> 6, d = c & 63;
    int b = bn >> 11, n = bn & 2047;
    ushort4 o;
    o.x = f2bf(v.x * 0.125f); o.y = f2bf(v.y * 0.125f);
    o.z = f2bf(v.z * 0.125f); o.w = f2bf(v.w * 0.125f);
    *reinterpret_cast<ushort4*>(Qh + (((size_t)(b*8+h) * 2048 + n) * 64 + d)) = o;
}

// G = sigmoid(X @ W^T + b1 + b2), bf16 out, layout [b,h,n,64]
__global__ __launch_bounds__(256) void k_gate(const float* __restrict__ X, const float* __restrict__ W,
        const float* __restrict__ b1, const float* __restrict__ b2,
        unsigned short* __restrict__ out) {
    __shared__ __align__(16) unsigned short Xs[64*88];
    __shared__ __align__(16) unsigned short Wsh[64*88];
    int t = threadIdx.x;
    int mbase = blockIdx.x * 64, nbase = blockIdx.y * 64;
    int w = t >> 6, lane = t & 63, l = lane & 15, quad = lane >> 4;
    int srow = t >> 2, sk = (t & 3) * 16;
    f32x4 acc[4] = {};
    for (int kk = 0; kk < 1024; kk += 64) {
        const float4* xs = reinterpret_cast<const float4*>(X + (size_t)(mbase+srow)*1024 + kk + sk);
        const float4* wsp = reinterpret_cast<const float4*>(W + (size_t)(nbase+srow)*1024 + kk + sk);
        #pragma unroll
        for (int i = 0; i < 4; ++i) {
            float4 xv = xs[i], wv = wsp[i];
            ushort4 xo, wo;
            xo.x=f2bf(xv.x); xo.y=f2bf(xv.y); xo.z=f2bf(xv.z); xo.w=f2bf(xv.w);
            wo.x=f2bf(wv.x); wo.y=f2bf(wv.y); wo.z=f2bf(wv.z); wo.w=f2bf(wv.w);
            *reinterpret_cast<ushort4*>(&Xs[srow*88 + sk + i*4]) = xo;
            *reinterpret_cast<ushort4*>(&Wsh[srow*88 + sk + i*4]) = wo;
        }
        __syncthreads();
        short8 a0 = *reinterpret_cast<const short8*>(&Xs[(w*16+l)*88 + quad*8]);
        short8 a1 = *reinterpret_cast<const short8*>(&Xs[(w*16+l)*88 + 32 + quad*8]);
        #pragma unroll
        for (int nt = 0; nt < 4; ++nt) {
            short8 bq0 = *reinterpret_cast<const short8*>(&Wsh[(l+16*nt)*88 + quad*8]);
            short8 bq1 = *reinterpret_cast<const short8*>(&Wsh[(l+16*nt)*88 + 32 + quad*8]);
            acc[nt] = __builtin_amdgcn_mfma_f32_16x16x32_bf16(a0, bq0, acc[nt], 0, 0, 0);
            acc[nt] = __builtin_amdgcn_mfma_f32_16x16x32_bf16(a1, bq1, acc[nt], 0, 0, 0);
        }
        __syncthreads();
    }
    #pragma unroll
    for (int nt = 0; nt < 4; ++nt) {
        int col = nbase + l + 16*nt;
        float bias = b1[col] + b2[col];
        #pragma unroll
        for (int reg = 0; reg < 4; ++reg) {
            int m = mbase + w*16 + quad*4 + reg;
            float x = acc[nt][reg] + bias;
            float g = 1.0f / (1.0f + __expf(-x));
            int b = m >> 11, n = m & 2047;
            int h = col >> 6, d = col & 63;
            out[(((size_t)(b*8+h)*2048 + n)*64 + d)] = f2bf(g);
        }
    }
}

// Vt[b,h,d,2048] = transpose of Vn[b,h,n,64]
__global__ __launch_bounds__(256) void k_vtrans(const unsigned short* __restrict__ Vn,
        unsigned short* __restrict__ Vt) {
    __shared__ __align__(16) unsigned short T[64*72];
    int bh = blockIdx.y;
    int n0 = blockIdx.x * 64;
    int t = threadIdx.x;
    int r = t >> 2, c = (t & 3) * 16;
    const unsigned short* src = Vn + ((size_t)bh*2048 + n0 + r)*64 + c;
    short8 v0 = *reinterpret_cast<const short8*>(src);
    short8 v1 = *reinterpret_cast<const short8*>(src + 8);
    *reinterpret_cast<short8*>(&T[r*72 + c]) = v0;
    *reinterpret_cast<short8*>(&T[r*72 + c + 8]) = v1;
    __syncthreads();
    int d = t >> 2, oc = (t & 3) * 16;
    unsigned short tmp[16];
    #pragma unroll
    for (int j = 0; j < 16; ++j) tmp[j] = T[(oc + j)*72 + d];
    unsigned short* dst = Vt + ((size_t)bh*64 + d)*2048 + n0 + oc;
    *reinterpret_cast<short8*>(dst) = *reinterpret_cast<short8*>(&tmp[0]);
    *reinterpret_cast<short8*>(dst + 8) = *reinterpret_cast<short8*>(&tmp[8]);
}

// Flash attention, heads 0..7. Barrier-free waves + split-K x2.
// Block = 256 threads / 4 waves: wave w -> qgroup (w>>1) of 16 rows, K-half (w&1).
// Grid 1024: (b, h, 32-row q-tile). attw/mask double-buffered in registers.
#define NEGBIG -1e30f
__global__ __launch_bounds__(256) void k_attn(const unsigned short* __restrict__ Qh,
        const unsigned short* __restrict__ Kh, const unsigned short* __restrict__ Vt,
        const float* __restrict__ attw, const int* __restrict__ mask,
        unsigned short* __restrict__ O) {
    __shared__ __align__(16) unsigned short Ps[4*16*88];
    __shared__ __align__(16) float Og[2][16*64];
    __shared__ float Ml[2][2][16];
    int bx = blockIdx.x;
    int qt = bx & 63, h = (bx >> 6) & 7, b = bx >> 9;
    int t = threadIdx.x, w = t >> 6, lane = t & 63, l = lane & 15, quad = lane >> 4;
    int qgrp = w >> 1, kh = w & 1;
    int qbase = qt * 32 + qgrp * 16;
    int bh = b*8 + h;
    const unsigned short* qp = Qh + ((size_t)bh*2048 + qbase + l)*64 + quad*8;
    short8 qf0 = *reinterpret_cast<const short8*>(qp);
    short8 qf1 = *reinterpret_cast<const short8*>(qp + 32);
    float m_r[4], l_r[4];
    f32x4 oacc[4] = {};
    #pragma unroll
    for (int r = 0; r < 4; ++r) { m_r[r] = NEGBIG; l_r[r] = 0.0f; }
    unsigned short* Pw = &Ps[w * 16*88];
    const size_t fbase = ((size_t)((b*16 + h)*2048 + qbase + quad*4))*2048 + l;
    const int khbase = kh * 1024;

    float awA[16], awB[16];
    int   mkA[16], mkB[16];

    // prologue: tile 0 of this half
    #pragma unroll
    for (int reg = 0; reg < 4; ++reg)
        #pragma unroll
        for (int nt = 0; nt < 4; ++nt) {
            size_t off = fbase + (size_t)reg*2048 + khbase + 16*nt;
            awA[reg*4+nt] = attw[off];
            mkA[reg*4+nt] = mask[off];
        }

    auto body = [&](int kbase, float* awc, int* mkc, float* awn, int* mkn, bool pref) {
        if (pref) {
            #pragma unroll
            for (int reg = 0; reg < 4; ++reg)
                #pragma unroll
                for (int nt = 0; nt < 4; ++nt) {
                    size_t off = fbase + (size_t)reg*2048 + (kbase + 64) + 16*nt;
                    awn[reg*4+nt] = attw[off];
                    mkn[reg*4+nt] = mask[off];
                }
        }
        // QK^T
        f32x4 s[4] = {};
        #pragma unroll
        for (int nt = 0; nt < 4; ++nt) {
            const unsigned short* kp = Kh + ((size_t)bh*2048 + kbase + l + 16*nt)*64 + quad*8;
            short8 k0 = *reinterpret_cast<const short8*>(kp);
            short8 k1 = *reinterpret_cast<const short8*>(kp + 32);
            s[nt] = __builtin_amdgcn_mfma_f32_16x16x32_bf16(qf0, k0, s[nt], 0, 0, 0);
            s[nt] = __builtin_amdgcn_mfma_f32_16x16x32_bf16(qf1, k1, s[nt], 0, 0, 0);
        }
        float sv[4][4];
        #pragma unroll
        for (int reg = 0; reg < 4; ++reg)
            #pragma unroll
            for (int nt = 0; nt < 4; ++nt)
                sv[nt][reg] = mkc[reg*4+nt] ? NEGBIG : s[nt][reg] * awc[reg*4+nt];
        float alpha[4];
        #pragma unroll
        for (int reg = 0; reg < 4; ++reg) {
            float rm = fmaxf(fmaxf(sv[0][reg], sv[1][reg]), fmaxf(sv[2][reg], sv[3][reg]));
            rm = fmaxf(rm, __shfl_xor(rm, 1));
            rm = fmaxf(rm, __shfl_xor(rm, 2));
            rm = fmaxf(rm, __shfl_xor(rm, 4));
            rm = fmaxf(rm, __shfl_xor(rm, 8));
            float mnew = fmaxf(m_r[reg], rm);
            alpha[reg] = __expf(m_r[reg] - mnew);
            m_r[reg] = mnew;
            float rs = 0.0f;
            #pragma unroll
            for (int nt = 0; nt < 4; ++nt) {
                float p = __expf(sv[nt][reg] - mnew);
                sv[nt][reg] = p;
                rs += p;
            }
            rs += __shfl_xor(rs, 1);
            rs += __shfl_xor(rs, 2);
            rs += __shfl_xor(rs, 4);
            rs += __shfl_xor(rs, 8);
            l_r[reg] = l_r[reg] * alpha[reg] + rs;
        }
        #pragma unroll
        for (int dt = 0; dt < 4; ++dt)
            #pragma unroll
            for (int reg = 0; reg < 4; ++reg)
                oacc[dt][reg] *= alpha[reg];
        // P: C-layout -> per-wave LDS -> A-layout
        #pragma unroll
        for (int reg = 0; reg < 4; ++reg)
            #pragma unroll
            for (int nt = 0; nt < 4; ++nt)
                Pw[(quad*4+reg)*88 + l + 16*nt] = f2bf(sv[nt][reg]);
        __builtin_amdgcn_s_waitcnt(0xC07F);  // lgkmcnt(0)
        short8 pf0 = *reinterpret_cast<const short8*>(&Pw[l*88 + quad*8]);
        short8 pf1 = *reinterpret_cast<const short8*>(&Pw[l*88 + 32 + quad*8]);
        #pragma unroll
        for (int dt = 0; dt < 4; ++dt) {
            const unsigned short* vp = Vt + ((size_t)bh*64 + l + 16*dt)*2048 + kbase + quad*8;
            short8 v0 = *reinterpret_cast<const short8*>(vp);
            short8 v1 = *reinterpret_cast<const short8*>(vp + 32);
            oacc[dt] = __builtin_amdgcn_mfma_f32_16x16x32_bf16(pf0, v0, oacc[dt], 0, 0, 0);
            oacc[dt] = __builtin_amdgcn_mfma_f32_16x16x32_bf16(pf1, v1, oacc[dt], 0, 0, 0);
        }
    };

    for (int i = 0; i < 8; ++i) {
        body(khbase + (2*i)*64,   awA, mkA, awB, mkB, true);
        body(khbase + (2*i+1)*64, awB, mkB, awA, mkA, i < 7);
    }

    // merge split-K partials: kh==1 publishes, kh==0 combines and writes
    if (kh == 1) {
        #pragma unroll
        for (int dt = 0; dt < 4; ++dt)
            #pragma unroll
            for (int reg = 0; reg < 4; ++reg)
                Og[qgrp][(quad*4+reg)*64 + l + 16*dt] = oacc[dt][reg];
        if (l == 0) {
            #pragma unroll
            for (int reg = 0; reg < 4; ++reg) {
                Ml[qgrp][0][quad*4+reg] = m_r[reg];
                Ml[qgrp][1][quad*4+reg] = l_r[reg];
            }
        }
    }
    __syncthreads();
    if (kh == 0) {
        #pragma unroll
        for (int reg = 0; reg < 4; ++reg) {
            int row = quad*4 + reg;
            float m1 = Ml[qgrp][0][row];
            float l1 = Ml[qgrp][1][row];
            float mstar = fmaxf(m_r[reg], m1);
            float a0 = __expf(m_r[reg] - mstar);
            float a1 = __expf(m1 - mstar);
            float inv = 1.0f / (l_r[reg]*a0 + l1*a1);
            int qr = qbase + row;
            #pragma unroll
            for (int dt = 0; dt < 4; ++dt) {
                float v1 = Og[qgrp][row*64 + l + 16*dt];
                float val = (oacc[dt][reg]*a0 + v1*a1) * inv;
                O[((size_t)b*2048 + qr)*512 + h*64 + l + 16*dt] = f2bf(val);
            }
        }
    }
}

// out[m,n] = sum_{k<512} O[m,k]*Wo[n,k] + c[n]
__global__ __launch_bounds__(256) void k_proj(const unsigned short* __restrict__ O,
        const float* __restrict__ Wo, const float* __restrict__ c, float* __restrict__ out) {
    __shared__ __align__(16) unsigned short Wsh[64*88];
    int t = threadIdx.x;
    int mb = blockIdx.x * 64, nb = blockIdx.y * 64;
    int w = t >> 6, lane = t & 63, l = lane & 15, quad = lane >> 4;
    int srow = t >> 2, sk = (t & 3) * 16;
    f32x4 acc[4] = {};
    for (int kb = 0; kb < 512; kb += 64) {
        const float4* wp = reinterpret_cast<const float4*>(Wo + (size_t)(nb+srow)*1024 + kb + sk);
        #pragma unroll
        for (int i = 0; i < 4; ++i) {
            float4 wv = wp[i];
            ushort4 wo2;
            wo2.x=f2bf(wv.x); wo2.y=f2bf(wv.y); wo2.z=f2bf(wv.z); wo2.w=f2bf(wv.w);
            *reinterpret_cast<ushort4*>(&Wsh[srow*88 + sk + i*4]) = wo2;
        }
        __syncthreads();
        const unsigned short* op = O + (size_t)(mb + w*16 + l)*512 + kb + quad*8;
        short8 a0 = *reinterpret_cast<const short8*>(op);
        short8 a1 = *reinterpret_cast<const short8*>(op + 32);
        #pragma unroll
        for (int nt = 0; nt < 4; ++nt) {
            short8 b0 = *reinterpret_cast<const short8*>(&Wsh[(l+16*nt)*88 + quad*8]);
            short8 b1 = *reinterpret_cast<const short8*>(&Wsh[(l+16*nt)*88 + 32 + quad*8]);
            acc[nt] = __builtin_amdgcn_mfma_f32_16x16x32_bf16(a0, b0, acc[nt], 0, 0, 0);
            acc[nt] = __builtin_amdgcn_mfma_f32_16x16x32_bf16(a1, b1, acc[nt], 0, 0, 0);
        }
        __syncthreads();
    }
    #pragma unroll
    for (int nt = 0; nt < 4; ++nt) {
        int coln = nb + l + 16*nt;
        float cv = c[coln];
        #pragma unroll
        for (int reg = 0; reg < 4; ++reg) {
            int row = mb + w*16 + quad*4 + reg;
            out[(size_t)row*1024 + coln] = acc[nt][reg] + cv;
        }
    }
}

extern "C" void kernel_launch(void* const* d_in, const int* in_sizes, int n_in,
                              void* d_out, int out_size, void* d_ws, size_t ws_size,
                              hipStream_t stream) {
    const float* queries = (const float*)d_in[0];
    const float* keys    = (const float*)d_in[1];
    const float* values  = (const float*)d_in[2];
    const int*   mask    = (const int*)d_in[3];
    const float* attw    = (const float*)d_in[4];
    const float* Wk_f    = (const float*)d_in[5];
    const float* bk_f    = (const float*)d_in[6];
    const float* kf_bias = (const float*)d_in[7];
    const float* Wv_f    = (const float*)d_in[8];
    const float* bv_f    = (const float*)d_in[9];
    const float* vf_bias = (const float*)d_in[10];
    // d_in[11] = k_sum: unused (heads>=8 output is exactly v_sum)
    const float* v_sum   = (const float*)d_in[12];
    const float* Wo      = (const float*)d_in[13];
    const float* bo      = (const float*)d_in[14];
    float* out = (float*)d_out;

    char* ws = (char*)d_ws;
    float* cvec = (float*)ws;                                   // 4 KB
    unsigned short* Qh = (unsigned short*)(ws + 4096);          // 4 MB
    unsigned short* Kh = Qh + (size_t)2*8*2048*64;              // 4 MB
    unsigned short* Vt = Kh + (size_t)2*8*2048*64;              // 4 MB
    unsigned short* Vn = Vt + (size_t)2*8*2048*64;              // 4 MB
    unsigned short* Ob = Vn;                                    // attn output overwrites Vn

    hipLaunchKernelGGL(k_compute_c, dim3(256), dim3(256), 0, stream, Wo, bo, v_sum, cvec);
    hipLaunchKernelGGL(k_convq, dim3(2048), dim3(256), 0, stream, queries, Qh);
    hipLaunchKernelGGL(k_gate, dim3(64, 8), dim3(256), 0, stream, keys, Wk_f, bk_f, kf_bias, Kh);
    hipLaunchKernelGGL(k_gate, dim3(64, 8), dim3(256), 0, stream, values, Wv_f, bv_f, vf_bias, Vn);
    hipLaunchKernelGGL(k_vtrans, dim3(32, 16), dim3(256), 0, stream, Vn, Vt);
    hipLaunchKernelGGL(k_attn, dim3(1024), dim3(256), 0, stream, Qh, Kh, Vt, attw, mask, Ob);
    hipLaunchKernelGGL(k_proj, dim3(64, 16), dim3(256), 0, stream, Ob, Wo, cvec, out);
}